// Round 4
// baseline (113.995 us; speedup 1.0000x reference)
//
#include <hip/hip_runtime.h>
#include <math.h>

// YOLOv1 loss: predicts/targets (8192, 7, 7, 30) fp32 -> scalar.
// Memory-bound streaming reduction; inputs 96.3 MB, HBM roofline ~15.3 us.
// v6 = v3 (async global_load_lds staging, two-kernel deterministic reduce)
//      + 128-cell/128-thread blocks: LDS 30720 B -> 5 blocks/CU (v3: 2).
//        5-way phase interleave keeps HBM saturated through each block's
//        vmcnt(0) drain + compute phase.
//      + LDS compute reads as float2 (cell base = 120 B, 8 B aligned).
// History: v4 last-block fusion (fence+atomic) = 145 us even w/o memory
//   traffic -> reverted. v5 direct float2 global loads (no LDS) = 113.1 vs
//   v3 110.3 -> stride-120 lanes lose to coalesced staging (poison fills
//   thrash L3 between iterations, inputs NOT cache-hot). Staging stays.

#define S7 7
#define CCH 30
#define CELLS_PER_BLOCK 128
#define THREADS 128
#define N_CELLS (8192 * S7 * S7)             // 401408
#define N_BLOCKS (N_CELLS / CELLS_PER_BLOCK) // 3136 exactly
#define EPSV 1e-6f

__device__ __forceinline__ float iou_cxcywh(float acx, float acy, float aw, float ah,
                                            float bcx, float bcy, float bw, float bh) {
    float ax1 = acx - aw * 0.5f, ax2 = acx + aw * 0.5f;
    float ay1 = acy - ah * 0.5f, ay2 = acy + ah * 0.5f;
    float bx1 = bcx - bw * 0.5f, bx2 = bcx + bw * 0.5f;
    float by1 = bcy - bh * 0.5f, by2 = bcy + bh * 0.5f;
    float iw = fmaxf(fminf(ax2, bx2) - fmaxf(ax1, bx1), 0.0f);
    float ih = fmaxf(fminf(ay2, by2) - fmaxf(ay1, by1), 0.0f);
    float inter = iw * ih;
    float area_a = (ax2 - ax1) * (ay2 - ay1);
    float area_b = (bx2 - bx1) * (by2 - by1);
    return inter / (area_a + area_b - inter);
}

__global__ __launch_bounds__(THREADS) void yolo_loss_partial(const float* __restrict__ pred,
                                                             const float* __restrict__ targ,
                                                             float* __restrict__ partial) {
    // p-tile: smem[0 .. 3840), t-tile: smem[3840 .. 7680)  (30720 B)
    __shared__ float smem[2 * CELLS_PER_BLOCK * CCH];

    const int tid = threadIdx.x;
    const int lane = tid & 63;
    const int wid = tid >> 6;                 // wave 0..1
    const int block_cell0 = blockIdx.x * CELLS_PER_BLOCK;

    // ---- Stage: async global->LDS, 30 chunks x 1024 B, 15 per wave ----
    // wave 0 -> p-tile, wave 1 -> t-tile. All 16B-aligned (block base =
    // 15360 B * blockIdx; chunks are 1024 B units). LDS layout LINEAR
    // (global_load_lds writes wave-uniform base + lane*16).
    {
        const float* gbase = (wid == 0) ? (pred + (size_t)block_cell0 * CCH)
                                        : (targ + (size_t)block_cell0 * CCH);
        float* lbase = smem + wid * (CELLS_PER_BLOCK * CCH);
#pragma unroll
        for (int i = 0; i < 15; ++i) {
            const float* gsrc = gbase + i * 256 + lane * 4;
            float* ldst = lbase + i * 256;    // wave-uniform base; HW adds lane*16
            __builtin_amdgcn_global_load_lds(
                (const __attribute__((address_space(1))) void*)gsrc,
                (__attribute__((address_space(3))) void*)ldst,
                16, 0, 0);
        }
    }
    __syncthreads();   // compiler emits s_waitcnt vmcnt(0) before s_barrier

    // ---- Compute: one cell per thread, LDS reads as float2 ----
    const float2* p2 = (const float2*)(smem + tid * CCH);
    const float2* t2 = (const float2*)(smem + CELLS_PER_BLOCK * CCH + tid * CCH);

    float2 pA = p2[0], pB = p2[1], pC = p2[2], pD = p2[3], pE = p2[4];
    float2 tA = t2[0], tB = t2[1], tC = t2[2];

    float px1 = pA.x, py1 = pA.y, pw1 = pB.x, ph1 = pB.y, pc1 = pC.x;
    float px2 = pC.y, py2 = pD.x, pw2 = pD.y, ph2 = pE.x, pc2 = pE.y;
    float tx = tA.x, ty = tA.y, tw = tB.x, th = tB.y, tc = tC.x;
    bool obj = tc > 0.0f;

    // class SSE (channels 10..29 = float2 indices 5..14)
    float cls = 0.0f;
#pragma unroll
    for (int k = 5; k < 15; ++k) {
        float2 pk = p2[k], tk = t2[k];
        float dx = pk.x - tk.x, dy = pk.y - tk.y;
        cls = fmaf(dx, dx, cls);
        cls = fmaf(dy, dy, cls);
    }

    const int cell = block_cell0 + tid;
    const int xy = cell % (S7 * S7);
    const float fx = (float)(xy % S7);
    const float fy = (float)(xy / S7);
    const float ratio = 1.0f / 7.0f;

    float tcx = (tx + fx) * ratio, tcy = (ty + fy) * ratio;
    float iou1 = iou_cxcywh((px1 + fx) * ratio, (py1 + fy) * ratio, pw1, ph1,
                            tcx, tcy, tw, th);
    float iou2 = iou_cxcywh((px2 + fx) * ratio, (py2 + fy) * ratio, pw2, ph2,
                            tcx, tcy, tw, th);
    bool resp = iou1 > iou2;

    float loss;
    if (obj) {
        float sx, sy, sw, sh, sc, siou;
        if (resp) { sx = px1; sy = py1; sw = pw1; sh = ph1; sc = pc1; siou = iou1; }
        else      { sx = px2; sy = py2; sw = pw2; sh = ph2; sc = pc2; siou = iou2; }
        float dx = sx - tx, dy = sy - ty;
        float dw = sqrtf(fmaxf(sw, EPSV)) - sqrtf(fmaxf(tw, EPSV));
        float dh = sqrtf(fmaxf(sh, EPSV)) - sqrtf(fmaxf(th, EPSV));
        float dc = sc - siou;
        loss = 5.0f * (dx * dx + dy * dy + dw * dw + dh * dh) + dc * dc + cls;
    } else {
        loss = 0.5f * (pc1 * pc1 + pc2 * pc2);
    }

    // ---- Block reduction: wave-64 shuffle, then 2 wave partials via LDS ----
    float v = loss;
#pragma unroll
    for (int off = 32; off > 0; off >>= 1) v += __shfl_down(v, off);

    __shared__ float red[2];
    if (lane == 0) red[wid] = v;
    __syncthreads();
    if (tid == 0) partial[blockIdx.x] = red[0] + red[1];
}

__global__ __launch_bounds__(256) void yolo_loss_final(const float* __restrict__ partial,
                                                       float* __restrict__ out) {
    float v = 0.0f;
    for (int i = threadIdx.x; i < N_BLOCKS; i += 256) v += partial[i];
#pragma unroll
    for (int off = 32; off > 0; off >>= 1) v += __shfl_down(v, off);

    __shared__ float red[4];
    const int lane = threadIdx.x & 63;
    const int wid = threadIdx.x >> 6;
    if (lane == 0) red[wid] = v;
    __syncthreads();
    if (threadIdx.x == 0) out[0] = red[0] + red[1] + red[2] + red[3];
}

extern "C" void kernel_launch(void* const* d_in, const int* in_sizes, int n_in,
                              void* d_out, int out_size, void* d_ws, size_t ws_size,
                              hipStream_t stream) {
    const float* predicts = (const float*)d_in[0];
    const float* targets  = (const float*)d_in[1];
    float* out = (float*)d_out;
    float* partial = (float*)d_ws;   // N_BLOCKS floats = 12544 B

    yolo_loss_partial<<<N_BLOCKS, THREADS, 0, stream>>>(predicts, targets, partial);
    yolo_loss_final<<<1, 256, 0, stream>>>(partial, out);
}

// Round 5
// 112.586 us; speedup vs baseline: 1.0125x; 1.0125x over previous
//
#include <hip/hip_runtime.h>
#include <math.h>

// YOLOv1 loss: predicts/targets (8192, 7, 7, 30) fp32 -> scalar.
// Memory-bound streaming reduction; inputs 96.3 MB, HBM roofline ~15.3 us.
// v7 = v3 CHAMPION REVERT (110.3 us). 256-cell/256-thread blocks, async
// global_load_lds staging (width 16), deterministic two-kernel reduce.
//
// Search history (all within-harness measured):
//   v3  110.3  <- this structure (champion)
//   v4  232    last-block fusion: per-block __threadfence + atomic ticket
//              serializes (~145 us even with zero HBM traffic). NEVER fuse
//              via device-scope fences here.
//   v5  113.1  no-LDS direct float2 loads (8% fewer bytes): stride-120
//              lanes lose to coalesced staging; inputs are NOT L3-hot
//              (the 2x256MiB poison fills thrash Infinity Cache).
//   v6  114.0  128-cell blocks (5 blocks/CU): occupancy wasn't the stall;
//              2x block count overhead dominates.
// Timed-path accounting: ~82 us = two 256 MiB harness poison fills (81% of
// HBM peak, untouchable) + ~18-20 us partial (floor 15.3) + ~2 us final +
// launch gaps. Controllable slack ~5 us; all attempts to capture it lost.

#define S7 7
#define CCH 30
#define CELLS_PER_BLOCK 256
#define N_CELLS (8192 * S7 * S7)             // 401408
#define N_BLOCKS (N_CELLS / CELLS_PER_BLOCK) // 1568 exactly
#define EPSV 1e-6f

__device__ __forceinline__ float iou_cxcywh(float acx, float acy, float aw, float ah,
                                            float bcx, float bcy, float bw, float bh) {
    float ax1 = acx - aw * 0.5f, ax2 = acx + aw * 0.5f;
    float ay1 = acy - ah * 0.5f, ay2 = acy + ah * 0.5f;
    float bx1 = bcx - bw * 0.5f, bx2 = bcx + bw * 0.5f;
    float by1 = bcy - bh * 0.5f, by2 = bcy + bh * 0.5f;
    float iw = fmaxf(fminf(ax2, bx2) - fmaxf(ax1, bx1), 0.0f);
    float ih = fmaxf(fminf(ay2, by2) - fmaxf(ay1, by1), 0.0f);
    float inter = iw * ih;
    float area_a = (ax2 - ax1) * (ay2 - ay1);
    float area_b = (bx2 - bx1) * (by2 - by1);
    return inter / (area_a + area_b - inter);
}

__global__ __launch_bounds__(256) void yolo_loss_partial(const float* __restrict__ pred,
                                                         const float* __restrict__ targ,
                                                         float* __restrict__ partial) {
    // p-tile: smem[0 .. 7680), t-tile: smem[7680 .. 15360)  (61440 B)
    __shared__ float smem[2 * CELLS_PER_BLOCK * CCH];

    const int tid = threadIdx.x;
    const int lane = tid & 63;
    const int wid = tid >> 6;                 // wave 0..3
    const int block_cell0 = blockIdx.x * CELLS_PER_BLOCK;

    // ---- Stage: async global->LDS, 60 chunks x 1024 B, 15 per wave ----
    // waves 0-1 stage the p-tile (chunks 0..29), waves 2-3 the t-tile.
    // Identical address stream to v3 (wave w covered chunks 15w..15w+14);
    // the tile select is just made explicitly wave-uniform. All addresses
    // 16B-aligned; LDS stays LINEAR (HW writes wave-uniform base + lane*16).
    {
        const float* gbase = (wid & 2) ? (targ + (size_t)block_cell0 * CCH)
                                       : (pred + (size_t)block_cell0 * CCH);
        float* lbase = smem + (wid & 2) * (CELLS_PER_BLOCK * CCH / 2);
        const int half = (wid & 1) * 15;      // chunks 0..14 or 15..29 of the tile
#pragma unroll
        for (int i = 0; i < 15; ++i) {
            const int c = half + i;           // wave-uniform
            const float* gsrc = gbase + c * 256 + lane * 4;
            float* ldst = lbase + c * 256;    // wave-uniform base; HW adds lane*16
            __builtin_amdgcn_global_load_lds(
                (const __attribute__((address_space(1))) void*)gsrc,
                (__attribute__((address_space(3))) void*)ldst,
                16, 0, 0);
        }
    }
    __syncthreads();   // compiler emits s_waitcnt vmcnt(0) before s_barrier

    // ---- Compute: one cell per thread, LDS reads as float2 ----
    const float2* p2 = (const float2*)(smem + tid * CCH);
    const float2* t2 = (const float2*)(smem + CELLS_PER_BLOCK * CCH + tid * CCH);

    float2 pA = p2[0], pB = p2[1], pC = p2[2], pD = p2[3], pE = p2[4];
    float2 tA = t2[0], tB = t2[1], tC = t2[2];

    float px1 = pA.x, py1 = pA.y, pw1 = pB.x, ph1 = pB.y, pc1 = pC.x;
    float px2 = pC.y, py2 = pD.x, pw2 = pD.y, ph2 = pE.x, pc2 = pE.y;
    float tx = tA.x, ty = tA.y, tw = tB.x, th = tB.y, tc = tC.x;
    bool obj = tc > 0.0f;

    // class SSE (channels 10..29 = float2 indices 5..14)
    float cls = 0.0f;
#pragma unroll
    for (int k = 5; k < 15; ++k) {
        float2 pk = p2[k], tk = t2[k];
        float dx = pk.x - tk.x, dy = pk.y - tk.y;
        cls = fmaf(dx, dx, cls);
        cls = fmaf(dy, dy, cls);
    }

    const int cell = block_cell0 + tid;
    const int xy = cell % (S7 * S7);
    const float fx = (float)(xy % S7);
    const float fy = (float)(xy / S7);
    const float ratio = 1.0f / 7.0f;

    float tcx = (tx + fx) * ratio, tcy = (ty + fy) * ratio;
    float iou1 = iou_cxcywh((px1 + fx) * ratio, (py1 + fy) * ratio, pw1, ph1,
                            tcx, tcy, tw, th);
    float iou2 = iou_cxcywh((px2 + fx) * ratio, (py2 + fy) * ratio, pw2, ph2,
                            tcx, tcy, tw, th);
    bool resp = iou1 > iou2;

    float loss;
    if (obj) {
        float sx, sy, sw, sh, sc, siou;
        if (resp) { sx = px1; sy = py1; sw = pw1; sh = ph1; sc = pc1; siou = iou1; }
        else      { sx = px2; sy = py2; sw = pw2; sh = ph2; sc = pc2; siou = iou2; }
        float dx = sx - tx, dy = sy - ty;
        float dw = sqrtf(fmaxf(sw, EPSV)) - sqrtf(fmaxf(tw, EPSV));
        float dh = sqrtf(fmaxf(sh, EPSV)) - sqrtf(fmaxf(th, EPSV));
        float dc = sc - siou;
        loss = 5.0f * (dx * dx + dy * dy + dw * dw + dh * dh) + dc * dc + cls;
    } else {
        loss = 0.5f * (pc1 * pc1 + pc2 * pc2);
    }

    // ---- Block reduction: wave-64 shuffle, then 4 wave partials via LDS ----
    float v = loss;
#pragma unroll
    for (int off = 32; off > 0; off >>= 1) v += __shfl_down(v, off);

    __shared__ float red[4];
    if (lane == 0) red[wid] = v;
    __syncthreads();
    if (tid == 0) partial[blockIdx.x] = red[0] + red[1] + red[2] + red[3];
}

__global__ __launch_bounds__(256) void yolo_loss_final(const float* __restrict__ partial,
                                                       float* __restrict__ out) {
    float v = 0.0f;
    for (int i = threadIdx.x; i < N_BLOCKS; i += 256) v += partial[i];
#pragma unroll
    for (int off = 32; off > 0; off >>= 1) v += __shfl_down(v, off);

    __shared__ float red[4];
    const int lane = threadIdx.x & 63;
    const int wid = threadIdx.x >> 6;
    if (lane == 0) red[wid] = v;
    __syncthreads();
    if (threadIdx.x == 0) out[0] = red[0] + red[1] + red[2] + red[3];
}

extern "C" void kernel_launch(void* const* d_in, const int* in_sizes, int n_in,
                              void* d_out, int out_size, void* d_ws, size_t ws_size,
                              hipStream_t stream) {
    const float* predicts = (const float*)d_in[0];
    const float* targets  = (const float*)d_in[1];
    float* out = (float*)d_out;
    float* partial = (float*)d_ws;   // N_BLOCKS floats = 6272 B

    yolo_loss_partial<<<N_BLOCKS, 256, 0, stream>>>(predicts, targets, partial);
    yolo_loss_final<<<1, 256, 0, stream>>>(partial, out);
}